// Round 5
// baseline (232.336 us; speedup 1.0000x reference)
//
#include <hip/hip_runtime.h>

constexpr int kRows  = 4096;
constexpr int kCols  = 11008;
constexpr int kRank  = 32;

constexpr int RT     = 16;    // rows per block tile (16 | 2048, codebook half stays uniform)
constexpr int CT     = 256;   // cols per tile
constexpr int PITCH  = 260;   // corr LDS pitch: breaks bank-stride, keeps b128 alignment
constexpr int JCHUNK = 4;     // tiles swept per block; 43 = 10*4 + 3 (last chunk ragged)
constexpr int NJT    = kCols / CT;   // 43

typedef __attribute__((ext_vector_type(8))) short short8;   // 8 x bf16 MFMA frag
typedef __attribute__((ext_vector_type(4))) float f32x4;    // MFMA accumulator / native float4

__device__ __forceinline__ unsigned short bf16_rne(float x) {
    union { float f; unsigned u; } v; v.f = x;
    return (unsigned short)((v.u + 0x7FFFu + ((v.u >> 16) & 1u)) >> 16);
}

// ---- prep: R transpose + bf16 convert only (L handled in-kernel now) ----
// Rbt[j][k] = bf16(R[k][j])  (11008 x 32)
__global__ __launch_bounds__(256) void prep_r(
    const float* __restrict__ Rm,
    unsigned short* __restrict__ Rbt)
{
    const int j = blockIdx.x * 256 + threadIdx.x;   // 43*256 = 11008, exact
    #pragma unroll
    for (int t = 0; t < 4; ++t) {
        short8 o;
        #pragma unroll
        for (int k = 0; k < 8; ++k)                 // coalesced across lanes per k
            o[k] = (short)bf16_rne(Rm[(t * 8 + k) * kCols + j]);
        *(short8*)(Rbt + j * kRank + t * 8) = o;    // 16B aligned
    }
}

// j-sweep block: owns 16 rows x 4 tiles. cb staging + A-frag once per block.
// corr ping-pong: MFMA for tile t+1 overlaps gather/store of tile t.
// One __syncthreads per tile. Phase-2 access shapes identical to the proven R1 kernel.
__global__ __launch_bounds__(256) void qw_fused(
    const float* __restrict__ codebooks,         // (2,256,8) fp32
    const int*   __restrict__ codes,             // flat 5,636,096 int32
    const float* __restrict__ scales,            // (11008,)
    const float* __restrict__ Lm,                // (4096,32) fp32
    const unsigned short* __restrict__ Rbt,      // (11008,32) bf16 (R transposed)
    float* __restrict__ outp)                    // (4096,11008) fp32
{
    __shared__ __attribute__((aligned(16))) float cb_lds[256 * 8];       // 8 KB: block's codebook half
    __shared__ __attribute__((aligned(16))) float corr[2][RT * PITCH];   // 2 x 16.6 KB ping-pong

    const int tid  = threadIdx.x;
    const int wave = tid >> 6;
    const int lane = tid & 63;
    const int n16  = lane & 15;
    const int q    = lane >> 4;
    const int i0   = blockIdx.y * RT;
    const int jt0  = blockIdx.x * JCHUNK;
    const int ntiles = (NJT - jt0 < JCHUNK) ? (NJT - jt0) : JCHUNK;

    // ---- stage this block's codebook half (2048 floats), once per block ----
    {
        const int sel = (i0 >= (kRows >> 1)) ? 1 : 0;         // block-uniform
        const f32x4* src = (const f32x4*)codebooks + (sel << 9);
        f32x4* dst = (f32x4*)cb_lds;
        dst[tid]       = src[tid];
        dst[tid + 256] = src[tid + 256];
    }

    // ---- A frag once per block (bit-identical to previous Lb path) ----
    short8 af;
    {
        const float* ap = Lm + (size_t)(i0 + n16) * kRank + (q << 3);
        const f32x4 a0 = *(const f32x4*)ap;
        const f32x4 a1 = *(const f32x4*)(ap + 4);
        af[0] = (short)bf16_rne(a0[0]); af[1] = (short)bf16_rne(a0[1]);
        af[2] = (short)bf16_rne(a0[2]); af[3] = (short)bf16_rne(a0[3]);
        af[4] = (short)bf16_rne(a1[0]); af[5] = (short)bf16_rne(a1[1]);
        af[6] = (short)bf16_rne(a1[2]); af[7] = (short)bf16_rne(a1[3]);
    }

    const int row_base = q << 2;               // C row = quad*4 + reg
    const int cbase    = (wave << 6) + n16;    // wave's 64-col slice

    auto compute_corr = [&](int jt, int buf) {
        const unsigned short* bbase =
            Rbt + (size_t)(jt * CT + (wave << 6) + n16) * kRank + (q << 3);
        #pragma unroll
        for (int nt = 0; nt < 4; ++nt) {
            const short8 bfr = *(const short8*)(bbase + nt * 16 * kRank);
            f32x4 acc = {0.f, 0.f, 0.f, 0.f};
            acc = __builtin_amdgcn_mfma_f32_16x16x32_bf16(af, bfr, acc, 0, 0, 0);
            const int ccol = cbase + nt * 16;
            #pragma unroll
            for (int r = 0; r < 4; ++r)
                corr[buf][(row_base + r) * PITCH + ccol] = acc[r];
        }
    };

    compute_corr(jt0, 0);                      // prologue: tile 0 -> buf 0

    const int lane4 = lane << 2;               // col offset in tile: 0..252 step 4
    const int rbase = wave;                    // 0..3

    for (int t = 0; t < ntiles; ++t) {
        __syncthreads();                       // corr[t&1] ready; corr[(t+1)&1] reads done
        if (t + 1 < ntiles)
            compute_corr(jt0 + t + 1, (t + 1) & 1);   // overlaps with phase 2 below

        const float* cbuf = corr[t & 1];
        const int j0 = (jt0 + t) * CT;
        #pragma unroll
        for (int p = 0; p < 4; ++p) {
            const int row = rbase + (p << 2);               // covers 0..15
            const int f = (i0 + row) * kCols + j0 + lane4;  // flat output index
            const int code = codes[f >> 3];
            const float scale = scales[f >> 12];
            const f32x4 w = *(const f32x4*)(cb_lds + (code << 3) + (lane4 & 4));
            const f32x4 c = *(const f32x4*)(cbuf + row * PITCH + lane4);
            f32x4 o;
            o[0] = w[0] * scale + c[0];
            o[1] = w[1] * scale + c[1];
            o[2] = w[2] * scale + c[2];
            o[3] = w[3] * scale + c[3];
            __builtin_nontemporal_store(o, (f32x4*)(outp + f));  // 1 KB contiguous per wave
        }
    }
}

extern "C" void kernel_launch(void* const* d_in, const int* in_sizes, int n_in,
                              void* d_out, int out_size, void* d_ws, size_t ws_size,
                              hipStream_t stream) {
    const float* codebooks = (const float*)d_in[0];
    const int*   codes     = (const int*)d_in[1];
    const float* scales    = (const float*)d_in[2];
    const float* Lm        = (const float*)d_in[3];
    const float* Rm        = (const float*)d_in[4];
    float* outp            = (float*)d_out;

    unsigned short* Rbt = (unsigned short*)d_ws;   // 11008*32*2 = 688 KB

    prep_r<<<dim3(43), dim3(256), 0, stream>>>(Rm, Rbt);

    dim3 grid((NJT + JCHUNK - 1) / JCHUNK, kRows / RT);   // (11, 256)
    qw_fused<<<grid, dim3(256), 0, stream>>>(codebooks, codes, scales, Lm, Rbt, outp);
}

// Round 6
// 224.402 us; speedup vs baseline: 1.0354x; 1.0354x over previous
//
#include <hip/hip_runtime.h>

constexpr int kRows  = 4096;
constexpr int kCols  = 11008;
constexpr int kRank  = 32;

constexpr int RT    = 16;    // rows per block tile (16 | 2048, codebook half stays uniform)
constexpr int CT    = 256;   // cols per block tile (11008 = 43 * 256, exact)
constexpr int PITCH = 260;   // corr LDS pitch: breaks bank-stride, keeps b128 alignment

typedef __attribute__((ext_vector_type(8))) short short8;   // 8 x bf16 MFMA frag
typedef __attribute__((ext_vector_type(4))) float f32x4;    // MFMA accumulator / native float4

__device__ __forceinline__ unsigned short bf16_rne(float x) {
    union { float f; unsigned u; } v; v.f = x;
    return (unsigned short)((v.u + 0x7FFFu + ((v.u >> 16) & 1u)) >> 16);
}

// ---- prep: one-shot bf16 conversion of L and R (R transposed) into workspace ----
__global__ __launch_bounds__(256) void prep(
    const float* __restrict__ Lm,
    const float* __restrict__ Rm,
    unsigned short* __restrict__ Lb,
    unsigned short* __restrict__ Rbt)
{
    const int tid = threadIdx.x;
    const int b   = blockIdx.x;
    if (b < 43) {                       // R transpose: 43*256 = 11008 threads, one col each
        const int j = b * 256 + tid;
        #pragma unroll
        for (int t = 0; t < 4; ++t) {
            short8 o;
            #pragma unroll
            for (int k = 0; k < 8; ++k)                       // coalesced across lanes per k
                o[k] = (short)bf16_rne(Rm[(t * 8 + k) * kCols + j]);
            *(short8*)(Rbt + j * kRank + t * 8) = o;          // 16B aligned
        }
    } else {                            // L convert: 64 blocks * 256 threads * 8 elems = 131072
        const int t0 = ((b - 43) * 256 + tid) * 8;
        const float4 a0 = *(const float4*)(Lm + t0);
        const float4 a1 = *(const float4*)(Lm + t0 + 4);
        short8 o;
        o[0] = (short)bf16_rne(a0.x); o[1] = (short)bf16_rne(a0.y);
        o[2] = (short)bf16_rne(a0.z); o[3] = (short)bf16_rne(a0.w);
        o[4] = (short)bf16_rne(a1.x); o[5] = (short)bf16_rne(a1.y);
        o[6] = (short)bf16_rne(a1.z); o[7] = (short)bf16_rne(a1.w);
        *(short8*)(Lb + t0) = o;
    }
}

// Proven-best structure (R1/R4): two-phase, RT=16, LDS = 8 KB cb + 16.6 KB corr
// = 24.6 KB -> 6 blocks/CU. Dense 1 KB wave stores, 128 B-contiguous codes loads.
// R6 tweak: codes/scales loads for all 4 p-iters hoisted ahead of gather+store.
__global__ __launch_bounds__(256, 6) void qw_fused(
    const float* __restrict__ codebooks,         // (2,256,8) fp32
    const int*   __restrict__ codes,             // flat 5,636,096 int32
    const float* __restrict__ scales,            // (11008,)
    const unsigned short* __restrict__ Lb,       // (4096,32) bf16
    const unsigned short* __restrict__ Rbt,      // (11008,32) bf16 (R transposed)
    float* __restrict__ outp)                    // (4096,11008) fp32
{
    __shared__ __attribute__((aligned(16))) float cb_lds[256 * 8];   // 8 KB: block's codebook half
    __shared__ __attribute__((aligned(16))) float corr[RT * PITCH];  // 16.6 KB fp32 corr tile

    const int tid = threadIdx.x;
    const int i0 = blockIdx.y * RT;
    const int j0 = blockIdx.x * CT;

    // ---- stage this block's codebook half to LDS (2048 floats = 512 float4) ----
    {
        const int sel = (i0 >= (kRows >> 1)) ? 1 : 0;         // block-uniform
        const f32x4* src = (const f32x4*)codebooks + (sel << 9);
        f32x4* dst = (f32x4*)cb_lds;
        dst[tid]       = src[tid];
        dst[tid + 256] = src[tid + 256];
    }

    // ---- phase 1: corr = L[i0:i0+16,:] @ R[:, j0:j0+256], 16 MFMA tiles over 4 waves ----
    {
        const int wave = tid >> 6;
        const int lane = tid & 63;
        const int n16  = lane & 15;
        const int q    = lane >> 4;

        // A frag: Lb[i0 + n16][q*8 .. q*8+7] -- one 16B load (same rows for all waves)
        const short8 af = *(const short8*)(Lb + (size_t)(i0 + n16) * kRank + (q << 3));

        // B frags: 4 col-tiles per wave, one 16B load each
        const unsigned short* bbase =
            Rbt + (size_t)(j0 + (wave << 6) + n16) * kRank + (q << 3);
        short8 bfr[4];
        #pragma unroll
        for (int nt = 0; nt < 4; ++nt)
            bfr[nt] = *(const short8*)(bbase + nt * 16 * kRank);

        const int row_base = q << 2;                 // C row = quad*4 + reg
        const int cbase    = (wave << 6) + n16;

        #pragma unroll
        for (int nt = 0; nt < 4; ++nt) {
            f32x4 acc = {0.f, 0.f, 0.f, 0.f};
            acc = __builtin_amdgcn_mfma_f32_16x16x32_bf16(af, bfr[nt], acc, 0, 0, 0);
            const int ccol = cbase + nt * 16;
            #pragma unroll
            for (int r = 0; r < 4; ++r)
                corr[(row_base + r) * PITCH + ccol] = acc[r];
        }
    }

    __syncthreads();

    // ---- phase 2: dequant gather + scale + corr add + fp32 store ----
    // All 4 codes/scales loads issued first (independent), then gathers + stores.
    {
        const int lane4 = (tid & 63) << 2;    // col offset in tile: 0..252 step 4
        const int rbase = tid >> 6;           // 0..3
        int   codev[4];
        float scalev[4];
        int   fv[4];
        #pragma unroll
        for (int p = 0; p < 4; ++p) {
            const int row = rbase + (p << 2);               // covers 0..15
            const int f = (i0 + row) * kCols + j0 + lane4;  // flat output index
            fv[p]     = f;
            codev[p]  = codes[f >> 3];                      // 128 B contiguous per wave
            scalev[p] = scales[f >> 12];
        }
        #pragma unroll
        for (int p = 0; p < 4; ++p) {
            const int row = rbase + (p << 2);
            const f32x4 w = *(const f32x4*)(cb_lds + (codev[p] << 3) + (lane4 & 4));
            const f32x4 c = *(const f32x4*)(corr + row * PITCH + lane4);
            f32x4 o;
            o[0] = w[0] * scalev[p] + c[0];
            o[1] = w[1] * scalev[p] + c[1];
            o[2] = w[2] * scalev[p] + c[2];
            o[3] = w[3] * scalev[p] + c[3];
            __builtin_nontemporal_store(o, (f32x4*)(outp + fv[p]));  // 1 KB contiguous per wave
        }
    }
}

extern "C" void kernel_launch(void* const* d_in, const int* in_sizes, int n_in,
                              void* d_out, int out_size, void* d_ws, size_t ws_size,
                              hipStream_t stream) {
    const float* codebooks = (const float*)d_in[0];
    const int*   codes     = (const int*)d_in[1];
    const float* scales    = (const float*)d_in[2];
    const float* Lm        = (const float*)d_in[3];
    const float* Rm        = (const float*)d_in[4];
    float* outp            = (float*)d_out;

    unsigned short* Lb  = (unsigned short*)d_ws;            // 4096*32*2   = 256 KB
    unsigned short* Rbt = Lb + kRows * kRank;               // 11008*32*2  = 688 KB

    prep<<<dim3(43 + 64), dim3(256), 0, stream>>>(Lm, Rm, Lb, Rbt);

    dim3 grid(kCols / CT, kRows / RT);   // (43, 256), exact cover
    qw_fused<<<grid, dim3(256), 0, stream>>>(codebooks, codes, scales, Lb, Rbt, outp);
}